// Round 8
// baseline (114.481 us; speedup 1.0000x reference)
//
#include <hip/hip_runtime.h>
#include <math.h>

#define NPTS 512
#define HID 128
#define RELD 64

typedef __attribute__((ext_vector_type(8))) short short8;
typedef __attribute__((ext_vector_type(4))) float f32x4;
typedef __attribute__((ext_vector_type(4))) int i32x4;

// ---------- precompute per-point tables ----------
// u_p[k] = sum_{c=1..6} feat_p[c] * W1[c][k]  (separable part of geom@W1)
// ui[p][k]  = u_p[k] + b1[k]  fp32, read wave-uniform / small-broadcast
// uj packed [k/8][p][8] bf16, read per-lane coalesced (16B/lane)
__global__ __launch_bounds__(256) void prep_tables(
    const float* __restrict__ pos, const float* __restrict__ color,
    const float* __restrict__ size, const float* __restrict__ W1,
    const float* __restrict__ b1, float* __restrict__ ui,
    unsigned short* __restrict__ uj, int npts)
{
  const int g = blockIdx.x * blockDim.x + threadIdx.x;
  const int k = g & (HID - 1), p = g >> 7;
  float v = pos[p * 2 + 0] * W1[1 * HID + k];
  v = fmaf(pos[p * 2 + 1], W1[2 * HID + k], v);
  v = fmaf(color[p * 3 + 0], W1[3 * HID + k], v);
  v = fmaf(color[p * 3 + 1], W1[4 * HID + k], v);
  v = fmaf(color[p * 3 + 2], W1[5 * HID + k], v);
  v = fmaf(size[p], W1[6 * HID + k], v);
  ui[g] = v + b1[k];
  const __bf16 vb = (__bf16)v;
  uj[((size_t)(k >> 3) * npts + p) * 8 + (k & 7)] = __builtin_bit_cast(unsigned short, vb);
}

// ---------- main: register-direct B-frags (no h bounce) + contiguous stores ----------
// Block = 256 threads = 4 waves, one tile of 256 pairs (one i, 256 j's).
// Lane (l15,lq) computes h for pairs {pt*16+l15 : pt=0..3} on k-octet ks*4+lq
// -> exactly the mfma_f32_16x16x32_bf16 B-fragment layout; no LDS transpose.
// W2^T bf16 swizzled in LDS (16KB); after MFMA a barrier lets the epilogue
// reuse the same LDS as per-wave bounce for fully-contiguous 1KB stores.
__global__ __launch_bounds__(256) void relgeom_mfma7(
    const float* __restrict__ pos, const float* __restrict__ W1,
    const float* __restrict__ ui, const unsigned short* __restrict__ uj,
    const float* __restrict__ W2, const float* __restrict__ b2,
    float* __restrict__ out, int npts)
{
  __shared__ __align__(16) char lds[16384];
  const int tid = threadIdx.x;
  const int lane = tid & 63, wid = tid >> 6;
  const int l15 = lane & 15, lq = lane >> 4;

  // stage W2 (fp32 [128][64]) -> LDS bf16 transposed [64 r][128 k], swizzled
#pragma unroll
  for (int n = 0; n < 32; ++n) {
    const int m = tid + 256 * n;
    const int k = m >> 6, r = m & 63;
    const __bf16 wb = (__bf16)W2[m];
    *(__bf16*)(lds + r * 256 + (((k >> 3) ^ (r & 7)) << 4) + (k & 7) * 2) = wb;
  }
  __syncthreads();

  const int bx = blockIdx.x;
  const int i  = (bx >> 1) & (NPTS - 1);
  const int b  = bx >> 10;
  const int pi = b * NPTS + i;                        // uniform -> SGPR
  const int jc = ((bx & 1) << 8) + (wid << 6) + l15;  // pt=0 pair column
  const int pj0 = b * NPTS + jc;

  const float pix = pos[pi * 2 + 0], piy = pos[pi * 2 + 1];   // uniform
  float dist[4];
  int pjs[4];
#pragma unroll
  for (int pt = 0; pt < 4; ++pt) {
    pjs[pt] = pj0 + pt * 16;
    const float dx = pix - pos[pjs[pt] * 2 + 0];
    const float dy = piy - pos[pjs[pt] * 2 + 1];
    dist[pt] = sqrtf(fmaf(dx, dx, fmaf(dy, dy, 1e-6f)));
  }

  const float* __restrict__ uirow = ui + (size_t)pi * HID;

  f32x4 acc[4][4];   // acc[rt][pt]: D[r][pair], r = rt*16+4lq+ri, pair = pt*16+l15
#pragma unroll
  for (int rt = 0; rt < 4; ++rt) {
    const f32x4 bb = *(const f32x4*)(b2 + rt * 16 + lq * 4);
#pragma unroll
    for (int pt = 0; pt < 4; ++pt) acc[rt][pt] = bb;
  }

#pragma unroll
  for (int ks = 0; ks < 4; ++ks) {
    const int kofs = ks * 32 + lq * 8;
    const f32x4 uiA = *(const f32x4*)(uirow + kofs);
    const f32x4 uiB = *(const f32x4*)(uirow + kofs + 4);
    const f32x4 w1A = *(const f32x4*)(W1 + kofs);        // W1 row 0 (dist)
    const f32x4 w1B = *(const f32x4*)(W1 + kofs + 4);
    const int o = ks * 4 + lq;                           // k-octet index

    short8 bfr[4];
#pragma unroll
    for (int pt = 0; pt < 4; ++pt) {
      union { i32x4 v; unsigned u[4]; } U;
      U.v = *(const i32x4*)(uj + ((size_t)o * npts + pjs[pt]) * 8);
      union { short s[8]; short8 v8; } hs;
#pragma unroll
      for (int e = 0; e < 8; ++e) {
        const float uiv = (e < 4) ? uiA[e] : uiB[e - 4];
        const float w1v = (e < 4) ? w1A[e] : w1B[e - 4];
        const unsigned w = U.u[e >> 1];
        const float ujf = __builtin_bit_cast(float, (e & 1) ? (w & 0xffff0000u) : (w << 16));
        float h = fmaf(dist[pt], w1v, uiv - ujf);
        const float h2 = h * h;
        const float wq = fmaf(h2, -0.1029534f, -2.3022077f);
        const float ex = __builtin_amdgcn_exp2f(h * wq);
        const float gel = h * __builtin_amdgcn_rcpf(1.0f + ex);
        const __bf16 hbf = (__bf16)gel;
        hs.s[e] = __builtin_bit_cast(short, hbf);
      }
      bfr[pt] = hs.v8;
    }

    // A frags = W2^T rows (r = rt*16+l15)
    short8 afr[4];
#pragma unroll
    for (int rt = 0; rt < 4; ++rt) {
      const int r = rt * 16 + l15;
      afr[rt] = *(const short8*)(lds + r * 256 + ((o ^ (r & 7)) << 4));
    }
#pragma unroll
    for (int pt = 0; pt < 4; ++pt)
#pragma unroll
      for (int rt = 0; rt < 4; ++rt)
        acc[rt][pt] = __builtin_amdgcn_mfma_f32_16x16x32_bf16(afr[rt], bfr[pt], acc[rt][pt], 0, 0, 0);
  }

  // W2 tile is dead now; reuse LDS as per-wave epilogue bounce after a barrier.
  __syncthreads();
  char* const ebase = lds + wid * 4096;

  const int pbase = bx * 256 + wid * 64;
#pragma unroll
  for (int pt = 0; pt < 4; ++pt) {
#pragma unroll
    for (int rt = 0; rt < 4; ++rt) {
      const int c = (rt * 4 + lq) ^ l15;         // swizzled 16B slot in pair's 256B
      *(f32x4*)(ebase + l15 * 256 + (c & 15) * 16) = acc[rt][pt];
    }
    float* const ob = out + (size_t)(pbase + pt * 16) * RELD;
#pragma unroll
    for (int m = 0; m < 4; ++m) {
      const int g = m * 64 + lane;               // 16B-chunk id within 4KB block
      const int pr = g >> 4;                     // local pair
      const int c = (g & 15) ^ pr;               // un-swizzle
      const f32x4 v = *(const f32x4*)(ebase + pr * 256 + (c & 15) * 16);
      *(f32x4*)(ob + (size_t)g * 4) = v;
    }
  }
}

// ---------- fallback (proven R2 kernel) if ws too small ----------
__global__ __launch_bounds__(256) void relgeom_mfma_fb(
    const float* __restrict__ pos, const float* __restrict__ color,
    const float* __restrict__ size, const float* __restrict__ W1,
    const float* __restrict__ b1, const float* __restrict__ W2,
    const float* __restrict__ b2, float* __restrict__ out)
{
  __shared__ __align__(16) char lds[16384 + 4 * 4096];
  const int tid = threadIdx.x;
  const int lane = tid & 63;
  const int wid = tid >> 6;
  const int l15 = lane & 15, lq = lane >> 4, l3 = lane & 3;
#pragma unroll
  for (int n = 0; n < 32; ++n) {
    const int m = tid + 256 * n;
    const int k = m >> 6, r = m & 63;
    const __bf16 wb = (__bf16)W2[m];
    *(__bf16*)(lds + r * 256 + (((k >> 3) ^ (r & 7)) << 4) + (k & 7) * 2) = wb;
  }
  __syncthreads();
  const int pbase = (blockIdx.x * 4 + wid) * 64;
  const int t = pbase + lane;
  const int j = t & (NPTS - 1);
  const int bi = t >> 9;
  const int i = bi & (NPTS - 1);
  const int b = bi >> 9;
  const int pi = b * NPTS + i, pj = b * NPTS + j;
  const float dx = pos[pi * 2 + 0] - pos[pj * 2 + 0];
  const float dy = pos[pi * 2 + 1] - pos[pj * 2 + 1];
  const float g0 = sqrtf(fmaf(dx, dx, fmaf(dy, dy, 1e-6f)));
  const float g3 = color[pi * 3 + 0] - color[pj * 3 + 0];
  const float g4 = color[pi * 3 + 1] - color[pj * 3 + 1];
  const float g5 = color[pi * 3 + 2] - color[pj * 3 + 2];
  const float g6 = size[pi] - size[pj];
  f32x4 acc[4][4];
#pragma unroll
  for (int nt = 0; nt < 4; ++nt) {
    const float bbv = b2[nt * 16 + l15];
#pragma unroll
    for (int s = 0; s < 4; ++s) acc[s][nt] = (f32x4){bbv, bbv, bbv, bbv};
  }
  char* const hbase = lds + 16384 + wid * 4096;
  for (int ks = 0; ks < 4; ++ks) {
    union { short s[32]; i32x4 v[4]; } hb;
#pragma unroll
    for (int kk = 0; kk < 32; ++kk) {
      const int k = ks * 32 + kk;
      float h = b1[k];
      h = fmaf(g0, W1[0 * HID + k], h);
      h = fmaf(dx, W1[1 * HID + k], h);
      h = fmaf(dy, W1[2 * HID + k], h);
      h = fmaf(g3, W1[3 * HID + k], h);
      h = fmaf(g4, W1[4 * HID + k], h);
      h = fmaf(g5, W1[5 * HID + k], h);
      h = fmaf(g6, W1[6 * HID + k], h);
      const float h2 = h * h;
      const float wq = fmaf(h2, -0.1029534f, -2.3022077f);
      const float ex = __builtin_amdgcn_exp2f(h * wq);
      const float gel = h * __builtin_amdgcn_rcpf(1.0f + ex);
      const __bf16 hbf = (__bf16)gel;
      hb.s[kk] = __builtin_bit_cast(short, hbf);
    }
#pragma unroll
    for (int d = 0; d < 4; ++d)
      *(i32x4*)(hbase + lane * 64 + ((d ^ l3) << 4)) = hb.v[d];
    short8 bfr[4];
#pragma unroll
    for (int nt = 0; nt < 4; ++nt) {
      const int r = nt * 16 + l15;
      bfr[nt] = *(const short8*)(lds + r * 256 + (((ks * 4 + lq) ^ (r & 7)) << 4));
    }
#pragma unroll
    for (int s = 0; s < 4; ++s) {
      const short8 af = *(const short8*)(hbase + (s * 16 + l15) * 64 + ((lq ^ l3) << 4));
#pragma unroll
      for (int nt = 0; nt < 4; ++nt)
        acc[s][nt] = __builtin_amdgcn_mfma_f32_16x16x32_bf16(af, bfr[nt], acc[s][nt], 0, 0, 0);
    }
  }
  float* const op = out + (size_t)pbase * RELD;
#pragma unroll
  for (int s = 0; s < 4; ++s)
#pragma unroll
    for (int nt = 0; nt < 4; ++nt)
#pragma unroll
      for (int ri = 0; ri < 4; ++ri)
        op[(s * 16 + lq * 4 + ri) * RELD + nt * 16 + l15] = acc[s][nt][ri];
}

extern "C" void kernel_launch(void* const* d_in, const int* in_sizes, int n_in,
                              void* d_out, int out_size, void* d_ws, size_t ws_size,
                              hipStream_t stream) {
  const float* pos   = (const float*)d_in[0];
  const float* color = (const float*)d_in[1];
  const float* size  = (const float*)d_in[2];
  const float* W1    = (const float*)d_in[3];
  const float* b1    = (const float*)d_in[4];
  const float* W2    = (const float*)d_in[5];
  const float* b2    = (const float*)d_in[6];
  float* out = (float*)d_out;

  const int B = in_sizes[0] / (NPTS * 2);
  const int npts = B * NPTS;
  const long long pairs = (long long)B * NPTS * NPTS;
  const int ntiles = (int)(pairs / 256);

  const size_t ui_bytes = (size_t)npts * HID * sizeof(float);
  const size_t uj_bytes = (size_t)npts * HID * sizeof(unsigned short);

  if (ws_size >= ui_bytes + uj_bytes) {
    float* ui = (float*)d_ws;
    unsigned short* uj = (unsigned short*)((char*)d_ws + ui_bytes);
    prep_tables<<<npts * HID / 256, 256, 0, stream>>>(pos, color, size, W1, b1, ui, uj, npts);
    relgeom_mfma7<<<ntiles, 256, 0, stream>>>(pos, W1, ui, uj, W2, b2, out, npts);
  } else {
    relgeom_mfma_fb<<<ntiles, 256, 0, stream>>>(pos, color, size, W1, b1, W2, b2, out);
  }
}

// Round 9
// 78.997 us; speedup vs baseline: 1.4492x; 1.4492x over previous
//
#include <hip/hip_runtime.h>
#include <math.h>

#define NPTS 512
#define HID 128
#define RELD 64

typedef __attribute__((ext_vector_type(8))) short short8;
typedef __attribute__((ext_vector_type(4))) float f32x4;
typedef __attribute__((ext_vector_type(4))) int i32x4;

// ---------- precompute per-point tables ----------
// u_p[k] = sum_{c=1..6} feat_p[c] * W1[c][k]  (separable part of geom@W1)
// ui[p][k]  = u_p[k] + b1[k]  fp32, read wave-uniform (s_load)
// uj packed [k/8][p][8] bf16, read per-lane fully coalesced (16B/lane)
__global__ __launch_bounds__(256) void prep_tables(
    const float* __restrict__ pos, const float* __restrict__ color,
    const float* __restrict__ size, const float* __restrict__ W1,
    const float* __restrict__ b1, float* __restrict__ ui,
    unsigned short* __restrict__ uj, int npts)
{
  const int g = blockIdx.x * blockDim.x + threadIdx.x;
  const int k = g & (HID - 1), p = g >> 7;
  float v = pos[p * 2 + 0] * W1[1 * HID + k];
  v = fmaf(pos[p * 2 + 1], W1[2 * HID + k], v);
  v = fmaf(color[p * 3 + 0], W1[3 * HID + k], v);
  v = fmaf(color[p * 3 + 1], W1[4 * HID + k], v);
  v = fmaf(color[p * 3 + 2], W1[5 * HID + k], v);
  v = fmaf(size[p], W1[6 * HID + k], v);
  ui[g] = v + b1[k];
  const __bf16 vb = (__bf16)v;
  uj[((size_t)(k >> 3) * npts + p) * 8 + (k & 7)] = __builtin_bit_cast(unsigned short, vb);
}

// ---------- main: R6 structure + non-temporal output stores ----------
__global__ __launch_bounds__(256) void relgeom_mfma8(
    const float* __restrict__ pos, const float* __restrict__ W1,
    const float* __restrict__ ui, const unsigned short* __restrict__ uj,
    const float* __restrict__ W2, const float* __restrict__ b2,
    float* __restrict__ out, int npts)
{
  __shared__ __align__(16) char lds[16384 + 4 * 4096];
  const int tid = threadIdx.x;
  const int lane = tid & 63, wid = tid >> 6;
  const int l15 = lane & 15, lq = lane >> 4, l3 = lane & 3;

  // stage W2 (fp32 [128][64]) -> LDS bf16 transposed [64 r][128 k], swizzled
#pragma unroll
  for (int n = 0; n < 32; ++n) {
    const int m = tid + 256 * n;
    const int k = m >> 6, r = m & 63;
    const __bf16 wb = (__bf16)W2[m];
    *(__bf16*)(lds + r * 256 + (((k >> 3) ^ (r & 7)) << 4) + (k & 7) * 2) = wb;
  }
  __syncthreads();

  // one i per block: everything i-side is a pure blockIdx expression -> SGPR
  const int bx = blockIdx.x;
  const int i  = (bx >> 1) & (NPTS - 1);
  const int b  = bx >> 10;
  const int pi = b * NPTS + i;                  // uniform
  const int j  = ((bx & 1) << 8) + tid;         // per-thread
  const int pj = b * NPTS + j;

  const float dx = pos[pi * 2 + 0] - pos[pj * 2 + 0];
  const float dy = pos[pi * 2 + 1] - pos[pj * 2 + 1];
  const float dist = sqrtf(fmaf(dx, dx, fmaf(dy, dy, 1e-6f)));

  const float* __restrict__ uirow = ui + (size_t)pi * HID;   // uniform -> s_load
  const float* __restrict__ w1d = W1;                        // row 0 (dist), uniform

  f32x4 acc[4][4];   // acc[rt][pt]; D[r][pair], row = rt*16+4*lq+ri, col(pair) = pt*16+l15
#pragma unroll
  for (int rt = 0; rt < 4; ++rt) {
    const f32x4 bb = *(const f32x4*)(b2 + rt * 16 + lq * 4);
#pragma unroll
    for (int pt = 0; pt < 4; ++pt) acc[rt][pt] = bb;
  }

  char* const hbase = lds + 16384 + wid * 4096;  // per-wave private bounce

  for (int ks = 0; ks < 4; ++ks) {
    union { i32x4 v[4]; unsigned u[16]; } U;
#pragma unroll
    for (int d = 0; d < 4; ++d)
      U.v[d] = *(const i32x4*)(uj + ((size_t)(ks * 4 + d) * npts + pj) * 8);

    union { short s[32]; i32x4 v[4]; } hb;
#pragma unroll
    for (int kk = 0; kk < 32; ++kk) {
      const int k = ks * 32 + kk;
      const unsigned w = U.u[kk >> 1];
      const float ujf = __builtin_bit_cast(float, (kk & 1) ? (w & 0xffff0000u) : (w << 16));
      float h = fmaf(dist, w1d[k], uirow[k] - ujf);
      const float h2 = h * h;
      const float wq = fmaf(h2, -0.1029534f, -2.3022077f);
      const float ex = __builtin_amdgcn_exp2f(h * wq);
      const float gel = h * __builtin_amdgcn_rcpf(1.0f + ex);
      const __bf16 hbf = (__bf16)gel;
      hb.s[kk] = __builtin_bit_cast(short, hbf);
    }
#pragma unroll
    for (int d = 0; d < 4; ++d)
      *(i32x4*)(hbase + lane * 64 + ((d ^ l3) << 4)) = hb.v[d];

    // A frags = W2^T rows (r = rt*16+l15), B frags = h rows (pair = pt*16+l15)
    short8 afr[4];
#pragma unroll
    for (int rt = 0; rt < 4; ++rt) {
      const int r = rt * 16 + l15;
      afr[rt] = *(const short8*)(lds + r * 256 + (((ks * 4 + lq) ^ (r & 7)) << 4));
    }
#pragma unroll
    for (int pt = 0; pt < 4; ++pt) {
      const int p = pt * 16 + l15;
      const short8 bfr = *(const short8*)(hbase + p * 64 + ((lq ^ (p & 3)) << 4));
#pragma unroll
      for (int rt = 0; rt < 4; ++rt)
        acc[rt][pt] = __builtin_amdgcn_mfma_f32_16x16x32_bf16(afr[rt], bfr, acc[rt][pt], 0, 0, 0);
    }
  }

  // epilogue: transpose via per-wave LDS, then fully-contiguous 1KB NT stores
  const int pbase = bx * 256 + wid * 64;
#pragma unroll
  for (int pt = 0; pt < 4; ++pt) {
#pragma unroll
    for (int rt = 0; rt < 4; ++rt) {
      const int c = (rt * 4 + lq) ^ l15;         // swizzled 16B slot in pair's 256B
      *(f32x4*)(hbase + l15 * 256 + (c & 15) * 16) = acc[rt][pt];
    }
    float* const ob = out + (size_t)(pbase + pt * 16) * RELD;
#pragma unroll
    for (int m = 0; m < 4; ++m) {
      const int g = m * 64 + lane;               // 16B-chunk id within 4KB block
      const int pr = g >> 4;                     // local pair
      const int c = (g & 15) ^ pr;               // un-swizzle
      const f32x4 v = *(const f32x4*)(hbase + pr * 256 + (c & 15) * 16);
      __builtin_nontemporal_store(v, (f32x4*)(ob + (size_t)g * 4));
    }
  }
}

// ---------- fallback (proven R2 kernel) if ws too small ----------
__global__ __launch_bounds__(256) void relgeom_mfma_fb(
    const float* __restrict__ pos, const float* __restrict__ color,
    const float* __restrict__ size, const float* __restrict__ W1,
    const float* __restrict__ b1, const float* __restrict__ W2,
    const float* __restrict__ b2, float* __restrict__ out)
{
  __shared__ __align__(16) char lds[16384 + 4 * 4096];
  const int tid = threadIdx.x;
  const int lane = tid & 63;
  const int wid = tid >> 6;
  const int l15 = lane & 15, lq = lane >> 4, l3 = lane & 3;
#pragma unroll
  for (int n = 0; n < 32; ++n) {
    const int m = tid + 256 * n;
    const int k = m >> 6, r = m & 63;
    const __bf16 wb = (__bf16)W2[m];
    *(__bf16*)(lds + r * 256 + (((k >> 3) ^ (r & 7)) << 4) + (k & 7) * 2) = wb;
  }
  __syncthreads();
  const int pbase = (blockIdx.x * 4 + wid) * 64;
  const int t = pbase + lane;
  const int j = t & (NPTS - 1);
  const int bi = t >> 9;
  const int i = bi & (NPTS - 1);
  const int b = bi >> 9;
  const int pi = b * NPTS + i, pj = b * NPTS + j;
  const float dx = pos[pi * 2 + 0] - pos[pj * 2 + 0];
  const float dy = pos[pi * 2 + 1] - pos[pj * 2 + 1];
  const float g0 = sqrtf(fmaf(dx, dx, fmaf(dy, dy, 1e-6f)));
  const float g3 = color[pi * 3 + 0] - color[pj * 3 + 0];
  const float g4 = color[pi * 3 + 1] - color[pj * 3 + 1];
  const float g5 = color[pi * 3 + 2] - color[pj * 3 + 2];
  const float g6 = size[pi] - size[pj];
  f32x4 acc[4][4];
#pragma unroll
  for (int nt = 0; nt < 4; ++nt) {
    const float bbv = b2[nt * 16 + l15];
#pragma unroll
    for (int s = 0; s < 4; ++s) acc[s][nt] = (f32x4){bbv, bbv, bbv, bbv};
  }
  char* const hbase = lds + 16384 + wid * 4096;
  for (int ks = 0; ks < 4; ++ks) {
    union { short s[32]; i32x4 v[4]; } hb;
#pragma unroll
    for (int kk = 0; kk < 32; ++kk) {
      const int k = ks * 32 + kk;
      float h = b1[k];
      h = fmaf(g0, W1[0 * HID + k], h);
      h = fmaf(dx, W1[1 * HID + k], h);
      h = fmaf(dy, W1[2 * HID + k], h);
      h = fmaf(g3, W1[3 * HID + k], h);
      h = fmaf(g4, W1[4 * HID + k], h);
      h = fmaf(g5, W1[5 * HID + k], h);
      h = fmaf(g6, W1[6 * HID + k], h);
      const float h2 = h * h;
      const float wq = fmaf(h2, -0.1029534f, -2.3022077f);
      const float ex = __builtin_amdgcn_exp2f(h * wq);
      const float gel = h * __builtin_amdgcn_rcpf(1.0f + ex);
      const __bf16 hbf = (__bf16)gel;
      hb.s[kk] = __builtin_bit_cast(short, hbf);
    }
#pragma unroll
    for (int d = 0; d < 4; ++d)
      *(i32x4*)(hbase + lane * 64 + ((d ^ l3) << 4)) = hb.v[d];
    short8 bfr[4];
#pragma unroll
    for (int nt = 0; nt < 4; ++nt) {
      const int r = nt * 16 + l15;
      bfr[nt] = *(const short8*)(lds + r * 256 + (((ks * 4 + lq) ^ (r & 7)) << 4));
    }
#pragma unroll
    for (int s = 0; s < 4; ++s) {
      const short8 af = *(const short8*)(hbase + (s * 16 + l15) * 64 + ((lq ^ l3) << 4));
#pragma unroll
      for (int nt = 0; nt < 4; ++nt)
        acc[s][nt] = __builtin_amdgcn_mfma_f32_16x16x32_bf16(af, bfr[nt], acc[s][nt], 0, 0, 0);
    }
  }
  float* const op = out + (size_t)pbase * RELD;
#pragma unroll
  for (int s = 0; s < 4; ++s)
#pragma unroll
    for (int nt = 0; nt < 4; ++nt)
#pragma unroll
      for (int ri = 0; ri < 4; ++ri)
        op[(s * 16 + lq * 4 + ri) * RELD + nt * 16 + l15] = acc[s][nt][ri];
}

extern "C" void kernel_launch(void* const* d_in, const int* in_sizes, int n_in,
                              void* d_out, int out_size, void* d_ws, size_t ws_size,
                              hipStream_t stream) {
  const float* pos   = (const float*)d_in[0];
  const float* color = (const float*)d_in[1];
  const float* size  = (const float*)d_in[2];
  const float* W1    = (const float*)d_in[3];
  const float* b1    = (const float*)d_in[4];
  const float* W2    = (const float*)d_in[5];
  const float* b2    = (const float*)d_in[6];
  float* out = (float*)d_out;

  const int B = in_sizes[0] / (NPTS * 2);
  const int npts = B * NPTS;
  const long long pairs = (long long)B * NPTS * NPTS;
  const int ntiles = (int)(pairs / 256);

  const size_t ui_bytes = (size_t)npts * HID * sizeof(float);
  const size_t uj_bytes = (size_t)npts * HID * sizeof(unsigned short);

  if (ws_size >= ui_bytes + uj_bytes) {
    float* ui = (float*)d_ws;
    unsigned short* uj = (unsigned short*)((char*)d_ws + ui_bytes);
    prep_tables<<<npts * HID / 256, 256, 0, stream>>>(pos, color, size, W1, b1, ui, uj, npts);
    relgeom_mfma8<<<ntiles, 256, 0, stream>>>(pos, W1, ui, uj, W2, b2, out, npts);
  } else {
    relgeom_mfma_fb<<<ntiles, 256, 0, stream>>>(pos, color, size, W1, b1, W2, b2, out);
  }
}

// Round 10
// 75.799 us; speedup vs baseline: 1.5103x; 1.0422x over previous
//
#include <hip/hip_runtime.h>
#include <math.h>

#define NPTS 512
#define HID 128
#define RELD 64

typedef __attribute__((ext_vector_type(8))) short short8;
typedef __attribute__((ext_vector_type(4))) float f32x4;
typedef __attribute__((ext_vector_type(2))) float f32x2;
typedef __attribute__((ext_vector_type(4))) int i32x4;

// ---------- precompute per-point tables ----------
// u_p[k] = sum_{c=1..6} feat_p[c] * W1[c][k]  (separable part of geom@W1)
// ui[p][k]  = u_p[k] + b1[k]  fp32, read wave-uniform (s_load)
// uj packed [k/8][p][8] bf16, read per-lane fully coalesced (16B/lane)
__global__ __launch_bounds__(256) void prep_tables(
    const float* __restrict__ pos, const float* __restrict__ color,
    const float* __restrict__ size, const float* __restrict__ W1,
    const float* __restrict__ b1, float* __restrict__ ui,
    unsigned short* __restrict__ uj, int npts)
{
  const int g = blockIdx.x * blockDim.x + threadIdx.x;
  const int k = g & (HID - 1), p = g >> 7;
  float v = pos[p * 2 + 0] * W1[1 * HID + k];
  v = fmaf(pos[p * 2 + 1], W1[2 * HID + k], v);
  v = fmaf(color[p * 3 + 0], W1[3 * HID + k], v);
  v = fmaf(color[p * 3 + 1], W1[4 * HID + k], v);
  v = fmaf(color[p * 3 + 2], W1[5 * HID + k], v);
  v = fmaf(size[p], W1[6 * HID + k], v);
  ui[g] = v + b1[k];
  const __bf16 vb = (__bf16)v;
  uj[((size_t)(k >> 3) * npts + p) * 8 + (k & 7)] = __builtin_bit_cast(unsigned short, vb);
}

// ---------- main: R6 structure, stage-1 rewritten on f32x2 (v_pk_* ops) ----------
__global__ __launch_bounds__(256) void relgeom_mfma9(
    const float* __restrict__ pos, const float* __restrict__ W1,
    const float* __restrict__ ui, const unsigned short* __restrict__ uj,
    const float* __restrict__ W2, const float* __restrict__ b2,
    float* __restrict__ out, int npts)
{
  __shared__ __align__(16) char lds[16384 + 4 * 4096];
  const int tid = threadIdx.x;
  const int lane = tid & 63, wid = tid >> 6;
  const int l15 = lane & 15, lq = lane >> 4, l3 = lane & 3;

  // stage W2 (fp32 [128][64]) -> LDS bf16 transposed [64 r][128 k], swizzled
#pragma unroll
  for (int n = 0; n < 32; ++n) {
    const int m = tid + 256 * n;
    const int k = m >> 6, r = m & 63;
    const __bf16 wb = (__bf16)W2[m];
    *(__bf16*)(lds + r * 256 + (((k >> 3) ^ (r & 7)) << 4) + (k & 7) * 2) = wb;
  }
  __syncthreads();

  // one i per block: everything i-side is a pure blockIdx expression -> SGPR
  const int bx = blockIdx.x;
  const int i  = (bx >> 1) & (NPTS - 1);
  const int b  = bx >> 10;
  const int pi = b * NPTS + i;                  // uniform
  const int j  = ((bx & 1) << 8) + tid;         // per-thread
  const int pj = b * NPTS + j;

  const float dx = pos[pi * 2 + 0] - pos[pj * 2 + 0];
  const float dy = pos[pi * 2 + 1] - pos[pj * 2 + 1];
  const float dist = sqrtf(fmaf(dx, dx, fmaf(dy, dy, 1e-6f)));
  const f32x2 distv = { dist, dist };

  const float* __restrict__ uirow = ui + (size_t)pi * HID;   // uniform -> s_load
  const float* __restrict__ w1d = W1;                        // row 0 (dist), uniform

  f32x4 acc[4][4];   // acc[rt][pt]; D[r][pair], row = rt*16+4*lq+ri, col(pair) = pt*16+l15
#pragma unroll
  for (int rt = 0; rt < 4; ++rt) {
    const f32x4 bb = *(const f32x4*)(b2 + rt * 16 + lq * 4);
#pragma unroll
    for (int pt = 0; pt < 4; ++pt) acc[rt][pt] = bb;
  }

  char* const hbase = lds + 16384 + wid * 4096;  // per-wave private bounce

  for (int ks = 0; ks < 4; ++ks) {
    union { i32x4 v[4]; unsigned u[16]; } U;
#pragma unroll
    for (int d = 0; d < 4; ++d)
      U.v[d] = *(const i32x4*)(uj + ((size_t)(ks * 4 + d) * npts + pj) * 8);

    union { short s[32]; i32x4 v[4]; } hb;
#pragma unroll
    for (int kk2 = 0; kk2 < 16; ++kk2) {         // two k's per iteration, pk math
      const int k0 = ks * 32 + kk2 * 2;
      const unsigned w = U.u[kk2];
      f32x2 ujf;
      ujf[0] = __builtin_bit_cast(float, w << 16);
      ujf[1] = __builtin_bit_cast(float, w & 0xffff0000u);
      const f32x2 uiv = { uirow[k0], uirow[k0 + 1] };    // uniform s_load pair
      const f32x2 w1v = { w1d[k0], w1d[k0 + 1] };        // uniform s_load pair
      const f32x2 h  = __builtin_elementwise_fma(distv, w1v, uiv - ujf);
      const f32x2 h2 = h * h;
      const f32x2 wq = __builtin_elementwise_fma(h2, (f32x2){-0.1029534f, -0.1029534f},
                                                 (f32x2){-2.3022077f, -2.3022077f});
      const f32x2 xs = h * wq;
      f32x2 ex;
      ex[0] = __builtin_amdgcn_exp2f(xs[0]);
      ex[1] = __builtin_amdgcn_exp2f(xs[1]);
      const f32x2 den = ex + 1.0f;
      f32x2 rc;
      rc[0] = __builtin_amdgcn_rcpf(den[0]);
      rc[1] = __builtin_amdgcn_rcpf(den[1]);
      const f32x2 gel = h * rc;
      hb.s[kk2 * 2 + 0] = __builtin_bit_cast(short, (__bf16)gel[0]);
      hb.s[kk2 * 2 + 1] = __builtin_bit_cast(short, (__bf16)gel[1]);
    }
#pragma unroll
    for (int d = 0; d < 4; ++d)
      *(i32x4*)(hbase + lane * 64 + ((d ^ l3) << 4)) = hb.v[d];

    // A frags = W2^T rows (r = rt*16+l15), B frags = h rows (pair = pt*16+l15)
    short8 afr[4];
#pragma unroll
    for (int rt = 0; rt < 4; ++rt) {
      const int r = rt * 16 + l15;
      afr[rt] = *(const short8*)(lds + r * 256 + (((ks * 4 + lq) ^ (r & 7)) << 4));
    }
#pragma unroll
    for (int pt = 0; pt < 4; ++pt) {
      const int p = pt * 16 + l15;
      const short8 bfr = *(const short8*)(hbase + p * 64 + ((lq ^ (p & 3)) << 4));
#pragma unroll
      for (int rt = 0; rt < 4; ++rt)
        acc[rt][pt] = __builtin_amdgcn_mfma_f32_16x16x32_bf16(afr[rt], bfr, acc[rt][pt], 0, 0, 0);
    }
  }

  // epilogue: transpose via per-wave LDS, then fully-contiguous 1KB stores
  const int pbase = bx * 256 + wid * 64;
#pragma unroll
  for (int pt = 0; pt < 4; ++pt) {
#pragma unroll
    for (int rt = 0; rt < 4; ++rt) {
      const int c = (rt * 4 + lq) ^ l15;         // swizzled 16B slot in pair's 256B
      *(f32x4*)(hbase + l15 * 256 + (c & 15) * 16) = acc[rt][pt];
    }
    float* const ob = out + (size_t)(pbase + pt * 16) * RELD;
#pragma unroll
    for (int m = 0; m < 4; ++m) {
      const int g = m * 64 + lane;               // 16B-chunk id within 4KB block
      const int pr = g >> 4;                     // local pair
      const int c = (g & 15) ^ pr;               // un-swizzle
      const f32x4 v = *(const f32x4*)(hbase + pr * 256 + (c & 15) * 16);
      *(f32x4*)(ob + (size_t)g * 4) = v;
    }
  }
}

// ---------- fallback (proven R2 kernel) if ws too small ----------
__global__ __launch_bounds__(256) void relgeom_mfma_fb(
    const float* __restrict__ pos, const float* __restrict__ color,
    const float* __restrict__ size, const float* __restrict__ W1,
    const float* __restrict__ b1, const float* __restrict__ W2,
    const float* __restrict__ b2, float* __restrict__ out)
{
  __shared__ __align__(16) char lds[16384 + 4 * 4096];
  const int tid = threadIdx.x;
  const int lane = tid & 63;
  const int wid = tid >> 6;
  const int l15 = lane & 15, lq = lane >> 4, l3 = lane & 3;
#pragma unroll
  for (int n = 0; n < 32; ++n) {
    const int m = tid + 256 * n;
    const int k = m >> 6, r = m & 63;
    const __bf16 wb = (__bf16)W2[m];
    *(__bf16*)(lds + r * 256 + (((k >> 3) ^ (r & 7)) << 4) + (k & 7) * 2) = wb;
  }
  __syncthreads();
  const int pbase = (blockIdx.x * 4 + wid) * 64;
  const int t = pbase + lane;
  const int j = t & (NPTS - 1);
  const int bi = t >> 9;
  const int i = bi & (NPTS - 1);
  const int b = bi >> 9;
  const int pi = b * NPTS + i, pj = b * NPTS + j;
  const float dx = pos[pi * 2 + 0] - pos[pj * 2 + 0];
  const float dy = pos[pi * 2 + 1] - pos[pj * 2 + 1];
  const float g0 = sqrtf(fmaf(dx, dx, fmaf(dy, dy, 1e-6f)));
  const float g3 = color[pi * 3 + 0] - color[pj * 3 + 0];
  const float g4 = color[pi * 3 + 1] - color[pj * 3 + 1];
  const float g5 = color[pi * 3 + 2] - color[pj * 3 + 2];
  const float g6 = size[pi] - size[pj];
  f32x4 acc[4][4];
#pragma unroll
  for (int nt = 0; nt < 4; ++nt) {
    const float bbv = b2[nt * 16 + l15];
#pragma unroll
    for (int s = 0; s < 4; ++s) acc[s][nt] = (f32x4){bbv, bbv, bbv, bbv};
  }
  char* const hbase = lds + 16384 + wid * 4096;
  for (int ks = 0; ks < 4; ++ks) {
    union { short s[32]; i32x4 v[4]; } hb;
#pragma unroll
    for (int kk = 0; kk < 32; ++kk) {
      const int k = ks * 32 + kk;
      float h = b1[k];
      h = fmaf(g0, W1[0 * HID + k], h);
      h = fmaf(dx, W1[1 * HID + k], h);
      h = fmaf(dy, W1[2 * HID + k], h);
      h = fmaf(g3, W1[3 * HID + k], h);
      h = fmaf(g4, W1[4 * HID + k], h);
      h = fmaf(g5, W1[5 * HID + k], h);
      h = fmaf(g6, W1[6 * HID + k], h);
      const float h2 = h * h;
      const float wq = fmaf(h2, -0.1029534f, -2.3022077f);
      const float ex = __builtin_amdgcn_exp2f(h * wq);
      const float gel = h * __builtin_amdgcn_rcpf(1.0f + ex);
      const __bf16 hbf = (__bf16)gel;
      hb.s[kk] = __builtin_bit_cast(short, hbf);
    }
#pragma unroll
    for (int d = 0; d < 4; ++d)
      *(i32x4*)(hbase + lane * 64 + ((d ^ l3) << 4)) = hb.v[d];
    short8 bfr[4];
#pragma unroll
    for (int nt = 0; nt < 4; ++nt) {
      const int r = nt * 16 + l15;
      bfr[nt] = *(const short8*)(lds + r * 256 + (((ks * 4 + lq) ^ (r & 7)) << 4));
    }
#pragma unroll
    for (int s = 0; s < 4; ++s) {
      const short8 af = *(const short8*)(hbase + (s * 16 + l15) * 64 + ((lq ^ l3) << 4));
#pragma unroll
      for (int nt = 0; nt < 4; ++nt)
        acc[s][nt] = __builtin_amdgcn_mfma_f32_16x16x32_bf16(af, bfr[nt], acc[s][nt], 0, 0, 0);
    }
  }
  float* const op = out + (size_t)pbase * RELD;
#pragma unroll
  for (int s = 0; s < 4; ++s)
#pragma unroll
    for (int nt = 0; nt < 4; ++nt)
#pragma unroll
      for (int ri = 0; ri < 4; ++ri)
        op[(s * 16 + lq * 4 + ri) * RELD + nt * 16 + l15] = acc[s][nt][ri];
}

extern "C" void kernel_launch(void* const* d_in, const int* in_sizes, int n_in,
                              void* d_out, int out_size, void* d_ws, size_t ws_size,
                              hipStream_t stream) {
  const float* pos   = (const float*)d_in[0];
  const float* color = (const float*)d_in[1];
  const float* size  = (const float*)d_in[2];
  const float* W1    = (const float*)d_in[3];
  const float* b1    = (const float*)d_in[4];
  const float* W2    = (const float*)d_in[5];
  const float* b2    = (const float*)d_in[6];
  float* out = (float*)d_out;

  const int B = in_sizes[0] / (NPTS * 2);
  const int npts = B * NPTS;
  const long long pairs = (long long)B * NPTS * NPTS;
  const int ntiles = (int)(pairs / 256);

  const size_t ui_bytes = (size_t)npts * HID * sizeof(float);
  const size_t uj_bytes = (size_t)npts * HID * sizeof(unsigned short);

  if (ws_size >= ui_bytes + uj_bytes) {
    float* ui = (float*)d_ws;
    unsigned short* uj = (unsigned short*)((char*)d_ws + ui_bytes);
    prep_tables<<<npts * HID / 256, 256, 0, stream>>>(pos, color, size, W1, b1, ui, uj, npts);
    relgeom_mfma9<<<ntiles, 256, 0, stream>>>(pos, W1, ui, uj, W2, b2, out, npts);
  } else {
    relgeom_mfma_fb<<<ntiles, 256, 0, stream>>>(pos, color, size, W1, b1, W2, b2, out);
  }
}